// Round 6
// baseline (5777.065 us; speedup 1.0000x reference)
//
#include <hip/hip_runtime.h>
#include <hip/hip_bf16.h>

// LSTMClassifier: B=64, T=2000, F=98, H=128, 2 bidir layers, FC 256->128->2
// Round-6 = round-5 resubmit (two consecutive acquisition timeouts; never ran).
// MFMA-based recurrence. One WG = 16 batches x 1 direction (8 WGs, 8 waves).
//  - Whh held as MFMA B-fragments in VGPRs (64 VGPR); h kept in LDS in A-fragment
//    layout (8KB double buffer, 4 ds_read_b128/wave/step).
//  - wave w owns n-tiles {w, w+8, w+16, w+24} == gates i,f,g,o for h-cols [16w,16w+16)
//    -> gate+c+h update fully in-lane (4 batches/lane), no shuffles, no redundancy.
//  - xg written by GEMM directly in C-fragment layout and used as MFMA C-initializer.
//  - one __syncthreads per step.

#define TT 2000
#define TC 250
#define NCH 8
#define BB 64
#define FF 98
#define HH 128

typedef __attribute__((ext_vector_type(8))) short short8;
typedef __attribute__((ext_vector_type(4))) short short4v;
typedef __attribute__((ext_vector_type(4))) float f32x4;
typedef unsigned long long ull;

__device__ __forceinline__ float fsig(float x) {
    float e = exp2f(-1.44269504f * x);
    return __builtin_amdgcn_rcpf(1.f + e);
}
__device__ __forceinline__ float ftanh(float x) {
    float ax = fabsf(x);
    float e = exp2f(-2.88539008f * ax);
    float t = (1.f - e) * __builtin_amdgcn_rcpf(1.f + e);
    return x < 0.f ? -t : t;
}
__device__ __forceinline__ float bfbits2f(unsigned u) {
    union { unsigned u; float f; } cv; cv.u = u << 16; return cv.f;
}
__device__ __forceinline__ short f2bfs(float f) {
    __hip_bfloat16 h = __float2bfloat16(f);
    short s; __builtin_memcpy(&s, &h, 2); return s;
}

// ---------- x [B,1,T,F] f32 -> X0 [T*B][128] bf16 (K padded 98->128) ----------
__global__ void conv_x_kernel(const float* __restrict__ x, __hip_bfloat16* __restrict__ X0) {
    int b = blockIdx.y;
    int t0 = blockIdx.x * 16;
    int tid = threadIdx.x;
    #pragma unroll
    for (int i = 0; i < 8; ++i) {
        int e = tid + i * 256;
        int r = e >> 7;
        int f = e & 127;
        float v = (f < FF) ? x[(size_t)b * TT * FF + (size_t)(t0 + r) * FF + f] : 0.f;
        X0[((size_t)(t0 + r) * BB + b) * 128 + f] = __float2bfloat16(v);
    }
}

// ---------- W_ih pair -> bf16 [1024][Kpad], bias = b_ih + b_hh ----------
__global__ void conv_w_kernel(const float* __restrict__ wf, const float* __restrict__ wb,
                              const float* __restrict__ bihf, const float* __restrict__ bhhf,
                              const float* __restrict__ bihb, const float* __restrict__ bhhb,
                              __hip_bfloat16* __restrict__ W, float* __restrict__ bias,
                              int Kin, int Kpad) {
    int j = blockIdx.x;            // 0..1023 ; rows 0-511 fwd, 512-1023 bwd
    int dir = j >> 9;
    int jj = j & 511;
    const float* w = dir ? wb : wf;
    for (int k = threadIdx.x; k < Kpad; k += blockDim.x)
        W[(size_t)j * Kpad + k] = __float2bfloat16(k < Kin ? w[(size_t)jj * Kin + k] : 0.f);
    if (threadIdx.x == 0)
        bias[j] = dir ? (bihb[jj] + bhhb[jj]) : (bihf[jj] + bhhf[jj]);
}

// ---------- Whh -> MFMA B-fragments: [dir][w][nt4][ks][lane][j] bf16 ----------
// value = Whh_dir[col][k], col = 16*(w+8*nt4) + (lane&15), k = ks*32 + (lane>>4)*8 + j
__global__ void conv_whh_kernel(const float* __restrict__ wf, const float* __restrict__ wb,
                                short* __restrict__ frags) {
    int t = blockIdx.x * 256 + threadIdx.x;   // 0..16383
    int l   = t & 63;
    int ks  = (t >> 6) & 3;
    int nt4 = (t >> 8) & 3;
    int w   = (t >> 10) & 7;
    int dir = t >> 13;
    const float* whh = dir ? wb : wf;
    int col = ((w + nt4 * 8) << 4) | (l & 15);
    int k0  = ks * 32 + (l >> 4) * 8;
    short8 v;
    #pragma unroll
    for (int j = 0; j < 8; ++j)
        v[j] = f2bfs(whh[(size_t)col * HH + k0 + j]);
    *(short8*)(frags + (size_t)t * 8) = v;
}

// ---------- chunk GEMM -> xg in C-fragment layout [tloc][bg][nt][lane][e] bf16 ----------
template<int K>
__launch_bounds__(256, 2)
__global__ void gemm_xg_kernel(const short* __restrict__ A,
                               const short* __restrict__ W,
                               const float* __restrict__ bias,
                               short* __restrict__ out,
                               int Aoff, int c0) {
    constexpr int KS = K / 32;
    int tid = threadIdx.x;
    int l = tid & 63;
    int wv = tid >> 6;
    int r_loc = blockIdx.x * 64;               // tile = one t (64 batch rows)
    int c_loc = blockIdx.y * 256 + wv * 64;    // dir-local col base
    int lr = l & 15;
    int lk = (l >> 4) * 8;

    f32x4 acc[4][4];
    #pragma unroll
    for (int a = 0; a < 4; ++a)
        #pragma unroll
        for (int b = 0; b < 4; ++b)
            acc[a][b] = (f32x4){0.f, 0.f, 0.f, 0.f};

    #pragma unroll
    for (int ks = 0; ks < KS; ++ks) {
        short8 af[4], bf[4];
        #pragma unroll
        for (int rt = 0; rt < 4; ++rt)
            af[rt] = *(const short8*)(A + (size_t)(Aoff + r_loc + rt * 16 + lr) * K + ks * 32 + lk);
        #pragma unroll
        for (int ct = 0; ct < 4; ++ct)
            bf[ct] = *(const short8*)(W + (size_t)(c0 + c_loc + ct * 16 + lr) * K + ks * 32 + lk);
        #pragma unroll
        for (int rt = 0; rt < 4; ++rt)
            #pragma unroll
            for (int ct = 0; ct < 4; ++ct)
                acc[rt][ct] = __builtin_amdgcn_mfma_f32_16x16x32_bf16(af[rt], bf[ct], acc[rt][ct], 0, 0, 0);
    }

    #pragma unroll
    for (int ct = 0; ct < 4; ++ct) {
        int col = c_loc + ct * 16 + lr;        // dir-local 0..511
        float bv = bias[c0 + col];
        int nt = col >> 4;                     // 0..31
        #pragma unroll
        for (int rt = 0; rt < 4; ++rt) {
            short4v pk;
            #pragma unroll
            for (int e = 0; e < 4; ++e)
                pk[e] = f2bfs(acc[rt][ct][e] + bv);
            *(short4v*)(out + ((((size_t)blockIdx.x * 4 + rt) * 32 + nt) * 64 + l) * 4) = pk;
        }
    }
}

// ---------- MFMA recurrence: WG = (batch-group of 16) x dir; 8 waves ----------
__launch_bounds__(512, 2)
__global__ void rec_kernel(const short* __restrict__ xgF,      // [TC][4][32][64][4] bf16
                           const short* __restrict__ xgB,
                           const short* __restrict__ whh_frags,
                           __hip_bfloat16* __restrict__ yout,  // [T][64][256] (layer0)
                           float* __restrict__ hstate,         // [2][64][128]
                           float* __restrict__ cstate,
                           int t0f, int t0b, int writeY, int first) {
    const int bg = blockIdx.x;       // 0..3
    const int dir = blockIdx.y;      // 0..1
    const int tid = threadIdx.x;
    const int l = tid & 63;
    const int w = tid >> 6;          // 0..7
    const short* xg = dir ? xgB : xgF;
    const int t0 = dir ? t0b : t0f;

    // Whh B-fragments: wave w, nt4 = gate, ks = k-step
    short8 bw[4][4];
    #pragma unroll
    for (int nt4 = 0; nt4 < 4; ++nt4)
        #pragma unroll
        for (int ks = 0; ks < 4; ++ks)
            bw[nt4][ks] = *(const short8*)(whh_frags +
                ((size_t)((((dir * 8 + w) * 4 + nt4) * 4 + ks)) * 64 + l) * 8);

    // h in A-fragment layout, double buffered: [buf][ks][lane][j]
    __shared__ __align__(16) short hA[2][4][64][8];
    short* hAf = (short*)hA;

    // lane set: hc = 16w + (l&15); batches b_loc = (l>>4)*4 + e
    const int hc = (w << 4) | (l & 15);
    const int wofs = (hc >> 5) * 512 + ((((hc >> 3) & 3) << 4) + ((l >> 4) << 2)) * 8 + (hc & 7);

    float c[4];
    if (first) {
        #pragma unroll
        for (int e = 0; e < 4; ++e) c[e] = 0.f;
        ((ull*)hAf)[tid] = 0;   // zero buffer 0 (2048 shorts = 512 ull)
    } else {
        #pragma unroll
        for (int e = 0; e < 4; ++e)
            c[e] = cstate[(size_t)(dir * BB + bg * 16 + ((l >> 4) << 2) + e) * HH + hc];
        #pragma unroll
        for (int i = 0; i < 4; ++i) {
            int m = tid * 4 + i;                  // 0..2047
            int j = m & 7;
            int lp = (m >> 3) & 63;
            int ks = m >> 9;
            int b = bg * 16 + (lp & 15);
            int hcm = ks * 32 + ((lp >> 4) & 3) * 8 + j;
            hAf[m] = f2bfs(hstate[(size_t)(dir * BB + b) * HH + hcm]);
        }
    }
    __syncthreads();

    // xg pointers: elem idx = (((tloc*4+bg)*32 + (w+8*nt4))*64 + l)*4
    const short* xp = xg + ((size_t)(bg * 32 + w) * 64 + l) * 4;
    const int tl0 = dir ? (TC - 1) : 0;
    const int tstep = dir ? -1 : 1;

    ull xc[4], xn[4];
    #pragma unroll
    for (int nt4 = 0; nt4 < 4; ++nt4)
        xc[nt4] = *(const ull*)(xp + (size_t)tl0 * 32768 + nt4 * 2048);

    float hout[4] = {0.f, 0.f, 0.f, 0.f};
    int cur = 0;

    for (int il = 0; il < TC; ++il) {
        const int tl = tl0 + il * tstep;
        if (il + 1 < TC) {
            const size_t tb = (size_t)(tl + tstep) * 32768;
            #pragma unroll
            for (int nt4 = 0; nt4 < 4; ++nt4)
                xn[nt4] = *(const ull*)(xp + tb + nt4 * 2048);
        }

        // A-fragments (h_t) from LDS
        short8 a[4];
        #pragma unroll
        for (int ks = 0; ks < 4; ++ks)
            a[ks] = *(const short8*)(hAf + cur * 2048 + ks * 512 + l * 8);

        // acc init from xg (C-fragment layout), then 16 MFMA
        f32x4 acc[4];
        #pragma unroll
        for (int nt4 = 0; nt4 < 4; ++nt4)
            #pragma unroll
            for (int e = 0; e < 4; ++e)
                acc[nt4][e] = bfbits2f((unsigned)((xc[nt4] >> (16 * e)) & 0xFFFFu));
        #pragma unroll
        for (int ks = 0; ks < 4; ++ks)
            #pragma unroll
            for (int nt4 = 0; nt4 < 4; ++nt4)
                acc[nt4] = __builtin_amdgcn_mfma_f32_16x16x32_bf16(a[ks], bw[nt4][ks], acc[nt4], 0, 0, 0);

        // gates: acc[0]=i, acc[1]=f, acc[2]=g, acc[3]=o ; in-lane update, 4 batches
        short* wp = hAf + (cur ^ 1) * 2048 + wofs;
        #pragma unroll
        for (int e = 0; e < 4; ++e) {
            float gi = fsig(acc[0][e]);
            float gf = fsig(acc[1][e]);
            float gg = ftanh(acc[2][e]);
            float go = fsig(acc[3][e]);
            c[e] = fmaf(gf, c[e], gi * gg);
            float h = go * ftanh(c[e]);
            hout[e] = h;
            short hb = f2bfs(h);
            wp[e * 8] = hb;
            if (writeY) {
                __hip_bfloat16 hh; __builtin_memcpy(&hh, &hb, 2);
                yout[((size_t)(t0 + tl) * BB + bg * 16 + ((l >> 4) << 2) + e) * 256 + dir * HH + hc] = hh;
            }
        }
        __syncthreads();
        cur ^= 1;
        #pragma unroll
        for (int nt4 = 0; nt4 < 4; ++nt4) xc[nt4] = xn[nt4];
    }

    // persist chunk-final state
    #pragma unroll
    for (int e = 0; e < 4; ++e) {
        int b = bg * 16 + ((l >> 4) << 2) + e;
        hstate[(size_t)(dir * BB + b) * HH + hc] = hout[e];
        cstate[(size_t)(dir * BB + b) * HH + hc] = c[e];
    }
}

// ---------- head: out[b] = clf( fc( [h_f, h_b] ) ) ----------
__global__ void fc_kernel(const float* __restrict__ hstate,   // [2][64][128]
                          const float* __restrict__ fcw, const float* __restrict__ fcb,
                          const float* __restrict__ clw, const float* __restrict__ clb,
                          float* __restrict__ out) {
    int b = blockIdx.x;
    int j = threadIdx.x;    // 0..127
    __shared__ float hrow[256];
    __shared__ float feat[128];
    hrow[j]       = hstate[(size_t)b * HH + j];
    hrow[j + 128] = hstate[(size_t)(BB + b) * HH + j];
    __syncthreads();
    float acc = fcb[j];
    #pragma unroll 4
    for (int k = 0; k < 256; ++k) acc = fmaf(hrow[k], fcw[(size_t)j * 256 + k], acc);
    feat[j] = acc;
    __syncthreads();
    if (j < 2) {
        float o = clb[j];
        #pragma unroll 4
        for (int k = 0; k < 128; ++k) o = fmaf(feat[k], clw[(size_t)j * 128 + k], o);
        out[b * 2 + j] = o;
    }
}

extern "C" void kernel_launch(void* const* d_in, const int* in_sizes, int n_in,
                              void* d_out, int out_size, void* d_ws, size_t ws_size,
                              hipStream_t stream) {
    const float* x        = (const float*)d_in[0];
    const float* w_ih_l0f = (const float*)d_in[1];
    const float* w_hh_l0f = (const float*)d_in[2];
    const float* b_ih_l0f = (const float*)d_in[3];
    const float* b_hh_l0f = (const float*)d_in[4];
    const float* w_ih_l0b = (const float*)d_in[5];
    const float* w_hh_l0b = (const float*)d_in[6];
    const float* b_ih_l0b = (const float*)d_in[7];
    const float* b_hh_l0b = (const float*)d_in[8];
    const float* w_ih_l1f = (const float*)d_in[9];
    const float* w_hh_l1f = (const float*)d_in[10];
    const float* b_ih_l1f = (const float*)d_in[11];
    const float* b_hh_l1f = (const float*)d_in[12];
    const float* w_ih_l1b = (const float*)d_in[13];
    const float* w_hh_l1b = (const float*)d_in[14];
    const float* b_ih_l1b = (const float*)d_in[15];
    const float* b_hh_l1b = (const float*)d_in[16];
    const float* fc_w     = (const float*)d_in[17];
    const float* fc_b     = (const float*)d_in[18];
    const float* clf_w    = (const float*)d_in[19];
    const float* clf_b    = (const float*)d_in[20];

    char* ws = (char*)d_ws;
    size_t off = 0;
    __hip_bfloat16* X0 = (__hip_bfloat16*)(ws + off); off += (size_t)TT * BB * 128 * 2;  // 32.8 MB
    __hip_bfloat16* y0 = (__hip_bfloat16*)(ws + off); off += (size_t)TT * BB * 256 * 2;  // 65.5 MB
    short* bufF        = (short*)(ws + off);          off += (size_t)TC * BB * 512 * 2;  // 16.4 MB
    short* bufB        = (short*)(ws + off);          off += (size_t)TC * BB * 512 * 2;  // 16.4 MB
    __hip_bfloat16* W0 = (__hip_bfloat16*)(ws + off); off += (size_t)1024 * 128 * 2;
    __hip_bfloat16* W1 = (__hip_bfloat16*)(ws + off); off += (size_t)1024 * 256 * 2;
    short* whhF        = (short*)(ws + off);          off += (size_t)16384 * 8 * 2;      // 256 KB
    float* bias0  = (float*)(ws + off); off += 1024 * 4;
    float* bias1  = (float*)(ws + off); off += 1024 * 4;
    float* hstate = (float*)(ws + off); off += 2 * BB * HH * 4;
    float* cstate = (float*)(ws + off); off += 2 * BB * HH * 4;
    // peak ws ~132 MB

    conv_x_kernel<<<dim3(TT / 16, BB), 256, 0, stream>>>(x, X0);
    conv_w_kernel<<<1024, 128, 0, stream>>>(w_ih_l0f, w_ih_l0b, b_ih_l0f, b_hh_l0f,
                                            b_ih_l0b, b_hh_l0b, W0, bias0, 98, 128);
    conv_w_kernel<<<1024, 256, 0, stream>>>(w_ih_l1f, w_ih_l1b, b_ih_l1f, b_hh_l1f,
                                            b_ih_l1b, b_hh_l1b, W1, bias1, 256, 256);

    dim3 ggrid(TC, 2);           // 250 t-tiles x 2 col-halves

    // layer 0
    conv_whh_kernel<<<64, 256, 0, stream>>>(w_hh_l0f, w_hh_l0b, whhF);
    for (int k = 0; k < NCH; ++k) {
        gemm_xg_kernel<128><<<ggrid, 256, 0, stream>>>(
            (const short*)X0, (const short*)W0, bias0, bufF, k * TC * BB, 0);
        gemm_xg_kernel<128><<<ggrid, 256, 0, stream>>>(
            (const short*)X0, (const short*)W0, bias0, bufB, (TT - (k + 1) * TC) * BB, 512);
        rec_kernel<<<dim3(4, 2), 512, 0, stream>>>(
            bufF, bufB, whhF, y0, hstate, cstate,
            k * TC, TT - (k + 1) * TC, 1, k == 0);
    }

    // layer 1 (only final h needed by the head)
    conv_whh_kernel<<<64, 256, 0, stream>>>(w_hh_l1f, w_hh_l1b, whhF);
    for (int k = 0; k < NCH; ++k) {
        gemm_xg_kernel<256><<<ggrid, 256, 0, stream>>>(
            (const short*)y0, (const short*)W1, bias1, bufF, k * TC * BB, 0);
        gemm_xg_kernel<256><<<ggrid, 256, 0, stream>>>(
            (const short*)y0, (const short*)W1, bias1, bufB, (TT - (k + 1) * TC) * BB, 512);
        rec_kernel<<<dim3(4, 2), 512, 0, stream>>>(
            bufF, bufB, whhF, y0, hstate, cstate,
            k * TC, TT - (k + 1) * TC, 0, k == 0);
    }

    fc_kernel<<<BB, 128, 0, stream>>>(hstate, fc_w, fc_b, clf_w, clf_b, (float*)d_out);
}

// Round 8
// 3207.128 us; speedup vs baseline: 1.8013x; 1.8013x over previous
//
#include <hip/hip_runtime.h>
#include <hip/hip_bf16.h>

// LSTMClassifier: B=64, T=2000, F=98, H=128, 2 bidir layers, FC 256->128->2
// Round-8 = round-7 resubmit (acquisition timeout; never ran). Audit re-verified.
// rec: 4 batches per WG -> 32 WGs on 32 CUs; batches on MFMA A-rows {0,4,8,12}
// so every lane owns exactly ONE valid C element (e=0) -> 1 gate-set/lane,
// no divergence, 4x less gate VALU per CU. GEMM/conv/xg layout byte-identical
// to round 6 (proven, absmax 4.9e-4); only rec_kernel's lane mapping changed.

#define TT 2000
#define TC 250
#define NCH 8
#define BB 64
#define FF 98
#define HH 128

typedef __attribute__((ext_vector_type(8))) short short8;
typedef __attribute__((ext_vector_type(4))) short short4v;
typedef __attribute__((ext_vector_type(4))) float f32x4;
typedef unsigned long long ull;

__device__ __forceinline__ float fsig(float x) {
    float e = exp2f(-1.44269504f * x);
    return __builtin_amdgcn_rcpf(1.f + e);
}
__device__ __forceinline__ float ftanh(float x) {
    float ax = fabsf(x);
    float e = exp2f(-2.88539008f * ax);
    float t = (1.f - e) * __builtin_amdgcn_rcpf(1.f + e);
    return x < 0.f ? -t : t;
}
__device__ __forceinline__ float bfbits2f(unsigned u) {
    union { unsigned u; float f; } cv; cv.u = u << 16; return cv.f;
}
__device__ __forceinline__ short f2bfs(float f) {
    __hip_bfloat16 h = __float2bfloat16(f);
    short s; __builtin_memcpy(&s, &h, 2); return s;
}

// ---------- x [B,1,T,F] f32 -> X0 [T*B][128] bf16 (K padded 98->128) ----------
__global__ void conv_x_kernel(const float* __restrict__ x, __hip_bfloat16* __restrict__ X0) {
    int b = blockIdx.y;
    int t0 = blockIdx.x * 16;
    int tid = threadIdx.x;
    #pragma unroll
    for (int i = 0; i < 8; ++i) {
        int e = tid + i * 256;
        int r = e >> 7;
        int f = e & 127;
        float v = (f < FF) ? x[(size_t)b * TT * FF + (size_t)(t0 + r) * FF + f] : 0.f;
        X0[((size_t)(t0 + r) * BB + b) * 128 + f] = __float2bfloat16(v);
    }
}

// ---------- W_ih pair -> bf16 [1024][Kpad], bias = b_ih + b_hh ----------
__global__ void conv_w_kernel(const float* __restrict__ wf, const float* __restrict__ wb,
                              const float* __restrict__ bihf, const float* __restrict__ bhhf,
                              const float* __restrict__ bihb, const float* __restrict__ bhhb,
                              __hip_bfloat16* __restrict__ W, float* __restrict__ bias,
                              int Kin, int Kpad) {
    int j = blockIdx.x;            // 0..1023 ; rows 0-511 fwd, 512-1023 bwd
    int dir = j >> 9;
    int jj = j & 511;
    const float* w = dir ? wb : wf;
    for (int k = threadIdx.x; k < Kpad; k += blockDim.x)
        W[(size_t)j * Kpad + k] = __float2bfloat16(k < Kin ? w[(size_t)jj * Kin + k] : 0.f);
    if (threadIdx.x == 0)
        bias[j] = dir ? (bihb[jj] + bhhb[jj]) : (bihf[jj] + bhhf[jj]);
}

// ---------- Whh -> MFMA B-fragments: [dir][w][nt4][ks][lane][j] bf16 ----------
// value = Whh_dir[col][k], col = 16*(w+8*nt4) + (lane&15), k = ks*32 + (lane>>4)*8 + j
__global__ void conv_whh_kernel(const float* __restrict__ wf, const float* __restrict__ wb,
                                short* __restrict__ frags) {
    int t = blockIdx.x * 256 + threadIdx.x;   // 0..16383
    int l   = t & 63;
    int ks  = (t >> 6) & 3;
    int nt4 = (t >> 8) & 3;
    int w   = (t >> 10) & 7;
    int dir = t >> 13;
    const float* whh = dir ? wb : wf;
    int col = ((w + nt4 * 8) << 4) | (l & 15);
    int k0  = ks * 32 + (l >> 4) * 8;
    short8 v;
    #pragma unroll
    for (int j = 0; j < 8; ++j)
        v[j] = f2bfs(whh[(size_t)col * HH + k0 + j]);
    *(short8*)(frags + (size_t)t * 8) = v;
}

// ---------- chunk GEMM -> xg in C-fragment layout [tloc][bg16][nt][lane][e] bf16 ----------
template<int K>
__launch_bounds__(256, 2)
__global__ void gemm_xg_kernel(const short* __restrict__ A,
                               const short* __restrict__ W,
                               const float* __restrict__ bias,
                               short* __restrict__ out,
                               int Aoff, int c0) {
    constexpr int KS = K / 32;
    int tid = threadIdx.x;
    int l = tid & 63;
    int wv = tid >> 6;
    int r_loc = blockIdx.x * 64;               // tile = one t (64 batch rows)
    int c_loc = blockIdx.y * 256 + wv * 64;    // dir-local col base
    int lr = l & 15;
    int lk = (l >> 4) * 8;

    f32x4 acc[4][4];
    #pragma unroll
    for (int a = 0; a < 4; ++a)
        #pragma unroll
        for (int b = 0; b < 4; ++b)
            acc[a][b] = (f32x4){0.f, 0.f, 0.f, 0.f};

    #pragma unroll
    for (int ks = 0; ks < KS; ++ks) {
        short8 af[4], bf[4];
        #pragma unroll
        for (int rt = 0; rt < 4; ++rt)
            af[rt] = *(const short8*)(A + (size_t)(Aoff + r_loc + rt * 16 + lr) * K + ks * 32 + lk);
        #pragma unroll
        for (int ct = 0; ct < 4; ++ct)
            bf[ct] = *(const short8*)(W + (size_t)(c0 + c_loc + ct * 16 + lr) * K + ks * 32 + lk);
        #pragma unroll
        for (int rt = 0; rt < 4; ++rt)
            #pragma unroll
            for (int ct = 0; ct < 4; ++ct)
                acc[rt][ct] = __builtin_amdgcn_mfma_f32_16x16x32_bf16(af[rt], bf[ct], acc[rt][ct], 0, 0, 0);
    }

    #pragma unroll
    for (int ct = 0; ct < 4; ++ct) {
        int col = c_loc + ct * 16 + lr;        // dir-local 0..511
        float bv = bias[c0 + col];
        int nt = col >> 4;                     // 0..31
        #pragma unroll
        for (int rt = 0; rt < 4; ++rt) {
            short4v pk;
            #pragma unroll
            for (int e = 0; e < 4; ++e)
                pk[e] = f2bfs(acc[rt][ct][e] + bv);
            *(short4v*)(out + ((((size_t)blockIdx.x * 4 + rt) * 32 + nt) * 64 + l) * 4) = pk;
        }
    }
}

// ---------- MFMA recurrence: WG = (batch-group of 4) x dir; 32 WGs, 8 waves ----------
// Batches sit on A-rows {0,4,8,12}: every lane's C e=0 slot is its (b,hc) gate-set.
__launch_bounds__(512, 2)
__global__ void rec_kernel(const short* __restrict__ xgF,      // [TC][4][32][64][4] bf16
                           const short* __restrict__ xgB,
                           const short* __restrict__ whh_frags,
                           __hip_bfloat16* __restrict__ yout,  // [T][64][256] (layer0)
                           float* __restrict__ hstate,         // [2][64][128]
                           float* __restrict__ cstate,
                           int t0f, int t0b, int writeY, int first) {
    const int bg = blockIdx.x;       // 0..15 (4 batches each)
    const int dir = blockIdx.y;      // 0..1
    const int tid = threadIdx.x;
    const int l = tid & 63;
    const int w = tid >> 6;          // 0..7
    const short* xg = dir ? xgB : xgF;
    const int t0 = dir ? t0b : t0f;

    // Whh B-fragments (unchanged layout): wave w, gate g, k-step ks
    short8 bw[4][4];
    #pragma unroll
    for (int g = 0; g < 4; ++g)
        #pragma unroll
        for (int ks = 0; ks < 4; ++ks)
            bw[g][ks] = *(const short8*)(whh_frags +
                ((size_t)((((dir * 8 + w) * 4 + g) * 4 + ks)) * 64 + l) * 8);

    // h in A-fragment layout, double buffered: [buf][ks][lane][j]
    __shared__ __align__(16) short hA[2][4][64][8];
    short* hAf = (short*)hA;

    const int hc = (w << 4) | (l & 15);   // h-column 0..127
    const int bl = l >> 4;                // batch-local 0..3
    const int b  = bg * 4 + bl;           // global batch
    // A-slot for (row = 4*bl, k = hc)
    const int wofs = (hc >> 5) * 512 + (((hc >> 3) & 3) * 16 + 4 * bl) * 8 + (hc & 7);
    const size_t sidx = (size_t)(dir * BB + b) * HH + hc;

    // zero both buffers (A-rows != 0 mod 4 must be 0 so garbage C rows stay clean)
    ((ull*)hAf)[tid] = 0;
    ((ull*)hAf)[tid + 512] = 0;
    __syncthreads();
    float cc = 0.f;
    if (!first) {
        cc = cstate[sidx];
        hAf[wofs] = f2bfs(hstate[sidx]);
    }
    __syncthreads();

    // xg addressing (round-6 C-fragment layout, re-derived for bg4):
    // idx(g) = (((tl*4 + (bg>>2))*32 + g*8 + w)*64 + ((bg&3)<<4 | (l&15)))*4 + bl
    const int tl0 = dir ? (TC - 1) : 0;
    const int tstep = dir ? -1 : 1;
    const int pstr = tstep * 32768;       // shorts per t step
    const int lg = ((bg & 3) << 4) | (l & 15);
    const short* p0 = xg + (size_t)tl0 * 32768 + ((((bg >> 2) * 32 + 0 * 8 + w) * 64 + lg) * 4 + bl);
    const short* p1 = xg + (size_t)tl0 * 32768 + ((((bg >> 2) * 32 + 1 * 8 + w) * 64 + lg) * 4 + bl);
    const short* p2 = xg + (size_t)tl0 * 32768 + ((((bg >> 2) * 32 + 2 * 8 + w) * 64 + lg) * 4 + bl);
    const short* p3 = xg + (size_t)tl0 * 32768 + ((((bg >> 2) * 32 + 3 * 8 + w) * 64 + lg) * 4 + bl);

    unsigned short xc0 = (unsigned short)*p0, xc1 = (unsigned short)*p1,
                   xc2 = (unsigned short)*p2, xc3 = (unsigned short)*p3;
    unsigned short xn0 = 0, xn1 = 0, xn2 = 0, xn3 = 0;

    __hip_bfloat16* yp = yout + ((size_t)(t0 + tl0) * BB + b) * 256 + dir * HH + hc;
    const ptrdiff_t ystr = (ptrdiff_t)tstep * BB * 256;

    float hlast = 0.f;
    int cur = 0;

    for (int il = 0; il < TC; ++il) {
        if (il + 1 < TC) {                // prefetch next step's 4 gate pre-activations
            xn0 = (unsigned short)p0[pstr];
            xn1 = (unsigned short)p1[pstr];
            xn2 = (unsigned short)p2[pstr];
            xn3 = (unsigned short)p3[pstr];
        }

        // A-fragments (h_t) from LDS
        short8 a0 = *(const short8*)(hAf + cur * 2048 + 0 * 512 + l * 8);
        short8 a1 = *(const short8*)(hAf + cur * 2048 + 1 * 512 + l * 8);
        short8 a2 = *(const short8*)(hAf + cur * 2048 + 2 * 512 + l * 8);
        short8 a3 = *(const short8*)(hAf + cur * 2048 + 3 * 512 + l * 8);

        // C-in: e=0 carries xg; e=1..3 rows are garbage-by-construction (A rows zero)
        f32x4 acc[4];
        acc[0] = (f32x4){bfbits2f(xc0), 0.f, 0.f, 0.f};
        acc[1] = (f32x4){bfbits2f(xc1), 0.f, 0.f, 0.f};
        acc[2] = (f32x4){bfbits2f(xc2), 0.f, 0.f, 0.f};
        acc[3] = (f32x4){bfbits2f(xc3), 0.f, 0.f, 0.f};
        #pragma unroll
        for (int g = 0; g < 4; ++g) {
            acc[g] = __builtin_amdgcn_mfma_f32_16x16x32_bf16(a0, bw[g][0], acc[g], 0, 0, 0);
            acc[g] = __builtin_amdgcn_mfma_f32_16x16x32_bf16(a1, bw[g][1], acc[g], 0, 0, 0);
            acc[g] = __builtin_amdgcn_mfma_f32_16x16x32_bf16(a2, bw[g][2], acc[g], 0, 0, 0);
            acc[g] = __builtin_amdgcn_mfma_f32_16x16x32_bf16(a3, bw[g][3], acc[g], 0, 0, 0);
        }

        // single gate-set per lane (e=0)
        float gi = fsig(acc[0][0]);
        float gf = fsig(acc[1][0]);
        float gg = ftanh(acc[2][0]);
        float go = fsig(acc[3][0]);
        cc = fmaf(gf, cc, gi * gg);
        float h = go * ftanh(cc);
        hlast = h;
        short hb = f2bfs(h);
        hAf[(cur ^ 1) * 2048 + wofs] = hb;
        if (writeY) {
            __hip_bfloat16 hh; __builtin_memcpy(&hh, &hb, 2);
            *yp = hh;
            yp += ystr;
        }
        __syncthreads();
        cur ^= 1;
        xc0 = xn0; xc1 = xn1; xc2 = xn2; xc3 = xn3;
        p0 += pstr; p1 += pstr; p2 += pstr; p3 += pstr;
    }

    hstate[sidx] = hlast;
    cstate[sidx] = cc;
}

// ---------- head: out[b] = clf( fc( [h_f, h_b] ) ) ----------
__global__ void fc_kernel(const float* __restrict__ hstate,   // [2][64][128]
                          const float* __restrict__ fcw, const float* __restrict__ fcb,
                          const float* __restrict__ clw, const float* __restrict__ clb,
                          float* __restrict__ out) {
    int b = blockIdx.x;
    int j = threadIdx.x;    // 0..127
    __shared__ float hrow[256];
    __shared__ float feat[128];
    hrow[j]       = hstate[(size_t)b * HH + j];
    hrow[j + 128] = hstate[(size_t)(BB + b) * HH + j];
    __syncthreads();
    float acc = fcb[j];
    #pragma unroll 4
    for (int k = 0; k < 256; ++k) acc = fmaf(hrow[k], fcw[(size_t)j * 256 + k], acc);
    feat[j] = acc;
    __syncthreads();
    if (j < 2) {
        float o = clb[j];
        #pragma unroll 4
        for (int k = 0; k < 128; ++k) o = fmaf(feat[k], clw[(size_t)j * 128 + k], o);
        out[b * 2 + j] = o;
    }
}

extern "C" void kernel_launch(void* const* d_in, const int* in_sizes, int n_in,
                              void* d_out, int out_size, void* d_ws, size_t ws_size,
                              hipStream_t stream) {
    const float* x        = (const float*)d_in[0];
    const float* w_ih_l0f = (const float*)d_in[1];
    const float* w_hh_l0f = (const float*)d_in[2];
    const float* b_ih_l0f = (const float*)d_in[3];
    const float* b_hh_l0f = (const float*)d_in[4];
    const float* w_ih_l0b = (const float*)d_in[5];
    const float* w_hh_l0b = (const float*)d_in[6];
    const float* b_ih_l0b = (const float*)d_in[7];
    const float* b_hh_l0b = (const float*)d_in[8];
    const float* w_ih_l1f = (const float*)d_in[9];
    const float* w_hh_l1f = (const float*)d_in[10];
    const float* b_ih_l1f = (const float*)d_in[11];
    const float* b_hh_l1f = (const float*)d_in[12];
    const float* w_ih_l1b = (const float*)d_in[13];
    const float* w_hh_l1b = (const float*)d_in[14];
    const float* b_ih_l1b = (const float*)d_in[15];
    const float* b_hh_l1b = (const float*)d_in[16];
    const float* fc_w     = (const float*)d_in[17];
    const float* fc_b     = (const float*)d_in[18];
    const float* clf_w    = (const float*)d_in[19];
    const float* clf_b    = (const float*)d_in[20];

    char* ws = (char*)d_ws;
    size_t off = 0;
    __hip_bfloat16* X0 = (__hip_bfloat16*)(ws + off); off += (size_t)TT * BB * 128 * 2;  // 32.8 MB
    __hip_bfloat16* y0 = (__hip_bfloat16*)(ws + off); off += (size_t)TT * BB * 256 * 2;  // 65.5 MB
    short* bufF        = (short*)(ws + off);          off += (size_t)TC * BB * 512 * 2;  // 16.4 MB
    short* bufB        = (short*)(ws + off);          off += (size_t)TC * BB * 512 * 2;  // 16.4 MB
    __hip_bfloat16* W0 = (__hip_bfloat16*)(ws + off); off += (size_t)1024 * 128 * 2;
    __hip_bfloat16* W1 = (__hip_bfloat16*)(ws + off); off += (size_t)1024 * 256 * 2;
    short* whhF        = (short*)(ws + off);          off += (size_t)16384 * 8 * 2;      // 256 KB
    float* bias0  = (float*)(ws + off); off += 1024 * 4;
    float* bias1  = (float*)(ws + off); off += 1024 * 4;
    float* hstate = (float*)(ws + off); off += 2 * BB * HH * 4;
    float* cstate = (float*)(ws + off); off += 2 * BB * HH * 4;
    // peak ws ~132 MB

    conv_x_kernel<<<dim3(TT / 16, BB), 256, 0, stream>>>(x, X0);
    conv_w_kernel<<<1024, 128, 0, stream>>>(w_ih_l0f, w_ih_l0b, b_ih_l0f, b_hh_l0f,
                                            b_ih_l0b, b_hh_l0b, W0, bias0, 98, 128);
    conv_w_kernel<<<1024, 256, 0, stream>>>(w_ih_l1f, w_ih_l1b, b_ih_l1f, b_hh_l1f,
                                            b_ih_l1b, b_hh_l1b, W1, bias1, 256, 256);

    dim3 ggrid(TC, 2);           // 250 t-tiles x 2 col-halves

    // layer 0
    conv_whh_kernel<<<64, 256, 0, stream>>>(w_hh_l0f, w_hh_l0b, whhF);
    for (int k = 0; k < NCH; ++k) {
        gemm_xg_kernel<128><<<ggrid, 256, 0, stream>>>(
            (const short*)X0, (const short*)W0, bias0, bufF, k * TC * BB, 0);
        gemm_xg_kernel<128><<<ggrid, 256, 0, stream>>>(
            (const short*)X0, (const short*)W0, bias0, bufB, (TT - (k + 1) * TC) * BB, 512);
        rec_kernel<<<dim3(16, 2), 512, 0, stream>>>(
            bufF, bufB, whhF, y0, hstate, cstate,
            k * TC, TT - (k + 1) * TC, 1, k == 0);
    }

    // layer 1 (only final h needed by the head)
    conv_whh_kernel<<<64, 256, 0, stream>>>(w_hh_l1f, w_hh_l1b, whhF);
    for (int k = 0; k < NCH; ++k) {
        gemm_xg_kernel<256><<<ggrid, 256, 0, stream>>>(
            (const short*)y0, (const short*)W1, bias1, bufF, k * TC * BB, 0);
        gemm_xg_kernel<256><<<ggrid, 256, 0, stream>>>(
            (const short*)y0, (const short*)W1, bias1, bufB, (TT - (k + 1) * TC) * BB, 512);
        rec_kernel<<<dim3(16, 2), 512, 0, stream>>>(
            bufF, bufB, whhF, y0, hstate, cstate,
            k * TC, TT - (k + 1) * TC, 0, k == 0);
    }

    fc_kernel<<<BB, 128, 0, stream>>>(hstate, fc_w, fc_b, clf_w, clf_b, (float*)d_out);
}

// Round 10
// 2486.733 us; speedup vs baseline: 2.3232x; 1.2897x over previous
//
#include <hip/hip_runtime.h>
#include <hip/hip_bf16.h>

// LSTMClassifier: B=64, T=2000, F=98, H=128, 2 bidir layers, FC 256->128->2
// Round-10 = round-9 resubmit (acquisition timeout; never ran). Audit re-verified:
// (1) rec instruction diet: xg [tl][b][hc][4gates] -> one dwordx2 load/step;
//     stale acc init (e!=0 rows provably stay 0: their A-rows never written).
// (2) GEMM-rec fusion: rec on 32 CUs, next chunk's GEMM rides along on idle CUs
//     (ping-pong chunk buffers, TC=125, ws ~132.5 MB == r8's proven footprint).
// Arithmetic identical to r8 (expect absmax exactly 0.0004882812).

#define TT 2000
#define TC 125
#define NCH 16
#define BB 64
#define FF 98
#define HH 128

typedef __attribute__((ext_vector_type(8))) short short8;
typedef __attribute__((ext_vector_type(4))) float f32x4;
typedef unsigned long long ull;

__device__ __forceinline__ float fsig(float x) {
    float e = exp2f(-1.44269504f * x);
    return __builtin_amdgcn_rcpf(1.f + e);
}
__device__ __forceinline__ float ftanh(float x) {
    float ax = fabsf(x);
    float e = exp2f(-2.88539008f * ax);
    float t = (1.f - e) * __builtin_amdgcn_rcpf(1.f + e);
    return x < 0.f ? -t : t;
}
__device__ __forceinline__ float bfbits2f(unsigned u) {
    union { unsigned u; float f; } cv; cv.u = u << 16; return cv.f;
}
__device__ __forceinline__ short f2bfs(float f) {
    __hip_bfloat16 h = __float2bfloat16(f);
    short s; __builtin_memcpy(&s, &h, 2); return s;
}

// ---------- x [B,1,T,F] f32 -> X0 [T*B][128] bf16 (K padded 98->128) ----------
__global__ void conv_x_kernel(const float* __restrict__ x, __hip_bfloat16* __restrict__ X0) {
    int b = blockIdx.y;
    int t0 = blockIdx.x * 16;
    int tid = threadIdx.x;
    #pragma unroll
    for (int i = 0; i < 8; ++i) {
        int e = tid + i * 256;
        int r = e >> 7;
        int f = e & 127;
        float v = (f < FF) ? x[(size_t)b * TT * FF + (size_t)(t0 + r) * FF + f] : 0.f;
        X0[((size_t)(t0 + r) * BB + b) * 128 + f] = __float2bfloat16(v);
    }
}

// ---------- W_ih pair -> bf16 [1024][Kpad], bias = b_ih + b_hh ----------
__global__ void conv_w_kernel(const float* __restrict__ wf, const float* __restrict__ wb,
                              const float* __restrict__ bihf, const float* __restrict__ bhhf,
                              const float* __restrict__ bihb, const float* __restrict__ bhhb,
                              __hip_bfloat16* __restrict__ W, float* __restrict__ bias,
                              int Kin, int Kpad) {
    int j = blockIdx.x;            // 0..1023 ; rows 0-511 fwd, 512-1023 bwd
    int dir = j >> 9;
    int jj = j & 511;
    const float* w = dir ? wb : wf;
    for (int k = threadIdx.x; k < Kpad; k += blockDim.x)
        W[(size_t)j * Kpad + k] = __float2bfloat16(k < Kin ? w[(size_t)jj * Kin + k] : 0.f);
    if (threadIdx.x == 0)
        bias[j] = dir ? (bihb[jj] + bhhb[jj]) : (bihf[jj] + bhhf[jj]);
}

// ---------- Whh -> MFMA B-fragments: [dir][w][g][ks][lane][j] bf16 ----------
__global__ void conv_whh_kernel(const float* __restrict__ wf, const float* __restrict__ wb,
                                short* __restrict__ frags) {
    int t = blockIdx.x * 256 + threadIdx.x;   // 0..16383
    int l   = t & 63;
    int ks  = (t >> 6) & 3;
    int nt4 = (t >> 8) & 3;
    int w   = (t >> 10) & 7;
    int dir = t >> 13;
    const float* whh = dir ? wb : wf;
    int col = ((w + nt4 * 8) << 4) | (l & 15);
    int k0  = ks * 32 + (l >> 4) * 8;
    short8 v;
    #pragma unroll
    for (int j = 0; j < 8; ++j)
        v[j] = f2bfs(whh[(size_t)col * HH + k0 + j]);
    *(short8*)(frags + (size_t)t * 8) = v;
}

// ---------- chunk GEMM body (512 thr): out [tl][64b][128hc][4g] bf16 ----------
template<int K>
__device__ __forceinline__ void gemm_body(const short* __restrict__ A,
                                          const short* __restrict__ W,
                                          const float* __restrict__ bias,
                                          short* __restrict__ out,
                                          int tl, int Aoff, int c0) {
    constexpr int KS = K / 32;
    int tid = threadIdx.x;
    int l = tid & 63;
    int wv = tid >> 6;             // 0..7
    int c_loc = wv * 64;           // dir-local col base (0..448)
    int lr = l & 15;
    int lk = (l >> 4) * 8;

    f32x4 acc[4][4];
    #pragma unroll
    for (int a = 0; a < 4; ++a)
        #pragma unroll
        for (int b = 0; b < 4; ++b)
            acc[a][b] = (f32x4){0.f, 0.f, 0.f, 0.f};

    #pragma unroll
    for (int ks = 0; ks < KS; ++ks) {
        short8 af[4], bf[4];
        #pragma unroll
        for (int rt = 0; rt < 4; ++rt)
            af[rt] = *(const short8*)(A + (size_t)(Aoff + tl * 64 + rt * 16 + lr) * K + ks * 32 + lk);
        #pragma unroll
        for (int ct = 0; ct < 4; ++ct)
            bf[ct] = *(const short8*)(W + (size_t)(c0 + c_loc + ct * 16 + lr) * K + ks * 32 + lk);
        #pragma unroll
        for (int rt = 0; rt < 4; ++rt)
            #pragma unroll
            for (int ct = 0; ct < 4; ++ct)
                acc[rt][ct] = __builtin_amdgcn_mfma_f32_16x16x32_bf16(af[rt], bf[ct], acc[rt][ct], 0, 0, 0);
    }

    #pragma unroll
    for (int ct = 0; ct < 4; ++ct) {
        int col = c_loc + ct * 16 + lr;        // dir-local 0..511
        float bv = bias[c0 + col];
        int gate = col >> 7;                   // 0..3
        int hc = col & 127;
        #pragma unroll
        for (int rt = 0; rt < 4; ++rt) {
            #pragma unroll
            for (int e = 0; e < 4; ++e) {
                int row = rt * 16 + (l >> 4) * 4 + e;   // batch 0..63 (m89 layout)
                out[(((size_t)tl * 64 + row) * 128 + hc) * 4 + gate] = f2bfs(acc[rt][ct][e] + bv);
            }
        }
    }
}

// ---------- standalone GEMM dispatch: grid 2*TC ----------
template<int K>
__launch_bounds__(512, 2)
__global__ void gemm_only_kernel(const short* __restrict__ A, const short* __restrict__ W,
                                 const float* __restrict__ bias,
                                 short* __restrict__ outF, short* __restrict__ outB,
                                 int AoffF, int AoffB) {
    int g = blockIdx.x;
    if (g < TC) gemm_body<K>(A, W, bias, outF, g, AoffF, 0);
    else        gemm_body<K>(A, W, bias, outB, g - TC, AoffB, 512);
}

// ---------- fused: blocks 0..31 = rec (bg x dir); blocks 32.. = next-chunk GEMM ----------
template<int K>
__launch_bounds__(512, 2)
__global__ void fused_kernel(const short* __restrict__ A,        // gemm input (X0 or y0)
                             const short* __restrict__ W,
                             const float* __restrict__ bias,
                             short* __restrict__ goutF, short* __restrict__ goutB,
                             int AoffF, int AoffB,
                             const short* __restrict__ xgF,      // rec src [TC][64][128][4]
                             const short* __restrict__ xgB,
                             const short* __restrict__ whh_frags,
                             __hip_bfloat16* __restrict__ yout,  // [T][64][256]
                             float* __restrict__ hstate, float* __restrict__ cstate,
                             int t0f, int t0b, int writeY, int first) {
    __shared__ __align__(16) short hA[2][4][64][8];

    if ((int)blockIdx.x >= 32) {
        int g = blockIdx.x - 32;
        if (g < TC) gemm_body<K>(A, W, bias, goutF, g, AoffF, 0);
        else        gemm_body<K>(A, W, bias, goutB, g - TC, AoffB, 512);
        return;
    }

    // ---------------- rec: 4 batches x 1 dir, batches on A-rows {0,4,8,12} ----------------
    const int bg = blockIdx.x & 15;
    const int dir = blockIdx.x >> 4;
    const int tid = threadIdx.x;
    const int l = tid & 63;
    const int w = tid >> 6;          // 0..7
    const short* xg = dir ? xgB : xgF;
    const int t0 = dir ? t0b : t0f;

    short8 bw[4][4];
    #pragma unroll
    for (int g = 0; g < 4; ++g)
        #pragma unroll
        for (int ks = 0; ks < 4; ++ks)
            bw[g][ks] = *(const short8*)(whh_frags +
                ((size_t)((((dir * 8 + w) * 4 + g) * 4 + ks)) * 64 + l) * 8);

    short* hAf = (short*)hA;
    const int hc = (w << 4) | (l & 15);   // h-column 0..127
    const int bl = l >> 4;                // batch-local 0..3
    const int b  = bg * 4 + bl;
    const int wofs = (hc >> 5) * 512 + (((hc >> 3) & 3) * 16 + 4 * bl) * 8 + (hc & 7);
    const size_t sidx = (size_t)(dir * BB + b) * HH + hc;

    ((ull*)hAf)[tid] = 0;
    ((ull*)hAf)[tid + 512] = 0;
    __syncthreads();
    float cc = 0.f;
    if (!first) {
        cc = cstate[sidx];
        hAf[wofs] = f2bfs(hstate[sidx]);
    }
    __syncthreads();

    const int tl0 = dir ? (TC - 1) : 0;
    const int tstep = dir ? -1 : 1;
    const int pstr = tstep * (BB * 128 * 4);   // +-32768 shorts per t
    const short* p = xg + (size_t)tl0 * (BB * 128 * 4) + ((size_t)b * 128 + hc) * 4;

    ull xc = *(const ull*)p;                   // 4 bf16 gates i,f,g,o
    ull xn = 0;

    __hip_bfloat16* yp = yout + ((size_t)(t0 + tl0) * BB + b) * 256 + dir * HH + hc;
    const ptrdiff_t ystr = (ptrdiff_t)tstep * BB * 256;

    float hlast = 0.f;
    int cur = 0;
    // stale-init acc: e!=0 stays 0 forever (their A-rows are always zero)
    f32x4 acc0 = {0.f,0.f,0.f,0.f}, acc1 = {0.f,0.f,0.f,0.f},
          acc2 = {0.f,0.f,0.f,0.f}, acc3 = {0.f,0.f,0.f,0.f};

    for (int il = 0; il < TC; ++il) {
        if (il + 1 < TC)
            xn = *(const ull*)(p + pstr);

        short8 a0 = *(const short8*)(hAf + cur * 2048 + 0 * 512 + l * 8);
        short8 a1 = *(const short8*)(hAf + cur * 2048 + 1 * 512 + l * 8);
        short8 a2 = *(const short8*)(hAf + cur * 2048 + 2 * 512 + l * 8);
        short8 a3 = *(const short8*)(hAf + cur * 2048 + 3 * 512 + l * 8);

        acc0[0] = bfbits2f((unsigned)(xc & 0xFFFFu));
        acc1[0] = bfbits2f((unsigned)((xc >> 16) & 0xFFFFu));
        acc2[0] = bfbits2f((unsigned)((xc >> 32) & 0xFFFFu));
        acc3[0] = bfbits2f((unsigned)((xc >> 48) & 0xFFFFu));

        acc0 = __builtin_amdgcn_mfma_f32_16x16x32_bf16(a0, bw[0][0], acc0, 0, 0, 0);
        acc0 = __builtin_amdgcn_mfma_f32_16x16x32_bf16(a1, bw[0][1], acc0, 0, 0, 0);
        acc0 = __builtin_amdgcn_mfma_f32_16x16x32_bf16(a2, bw[0][2], acc0, 0, 0, 0);
        acc0 = __builtin_amdgcn_mfma_f32_16x16x32_bf16(a3, bw[0][3], acc0, 0, 0, 0);
        acc1 = __builtin_amdgcn_mfma_f32_16x16x32_bf16(a0, bw[1][0], acc1, 0, 0, 0);
        acc1 = __builtin_amdgcn_mfma_f32_16x16x32_bf16(a1, bw[1][1], acc1, 0, 0, 0);
        acc1 = __builtin_amdgcn_mfma_f32_16x16x32_bf16(a2, bw[1][2], acc1, 0, 0, 0);
        acc1 = __builtin_amdgcn_mfma_f32_16x16x32_bf16(a3, bw[1][3], acc1, 0, 0, 0);
        acc2 = __builtin_amdgcn_mfma_f32_16x16x32_bf16(a0, bw[2][0], acc2, 0, 0, 0);
        acc2 = __builtin_amdgcn_mfma_f32_16x16x32_bf16(a1, bw[2][1], acc2, 0, 0, 0);
        acc2 = __builtin_amdgcn_mfma_f32_16x16x32_bf16(a2, bw[2][2], acc2, 0, 0, 0);
        acc2 = __builtin_amdgcn_mfma_f32_16x16x32_bf16(a3, bw[2][3], acc2, 0, 0, 0);
        acc3 = __builtin_amdgcn_mfma_f32_16x16x32_bf16(a0, bw[3][0], acc3, 0, 0, 0);
        acc3 = __builtin_amdgcn_mfma_f32_16x16x32_bf16(a1, bw[3][1], acc3, 0, 0, 0);
        acc3 = __builtin_amdgcn_mfma_f32_16x16x32_bf16(a2, bw[3][2], acc3, 0, 0, 0);
        acc3 = __builtin_amdgcn_mfma_f32_16x16x32_bf16(a3, bw[3][3], acc3, 0, 0, 0);

        float gi = fsig(acc0[0]);
        float gf = fsig(acc1[0]);
        float gg = ftanh(acc2[0]);
        float go = fsig(acc3[0]);
        cc = fmaf(gf, cc, gi * gg);
        float h = go * ftanh(cc);
        hlast = h;
        short hb = f2bfs(h);
        hAf[(cur ^ 1) * 2048 + wofs] = hb;
        if (writeY) {
            __hip_bfloat16 hh; __builtin_memcpy(&hh, &hb, 2);
            *yp = hh;
            yp += ystr;
        }
        __syncthreads();
        cur ^= 1;
        xc = xn;
        p += pstr;
    }

    hstate[sidx] = hlast;
    cstate[sidx] = cc;
}

// ---------- head: out[b] = clf( fc( [h_f, h_b] ) ) ----------
__global__ void fc_kernel(const float* __restrict__ hstate,   // [2][64][128]
                          const float* __restrict__ fcw, const float* __restrict__ fcb,
                          const float* __restrict__ clw, const float* __restrict__ clb,
                          float* __restrict__ out) {
    int b = blockIdx.x;
    int j = threadIdx.x;    // 0..127
    __shared__ float hrow[256];
    __shared__ float feat[128];
    hrow[j]       = hstate[(size_t)b * HH + j];
    hrow[j + 128] = hstate[(size_t)(BB + b) * HH + j];
    __syncthreads();
    float acc = fcb[j];
    #pragma unroll 4
    for (int k = 0; k < 256; ++k) acc = fmaf(hrow[k], fcw[(size_t)j * 256 + k], acc);
    feat[j] = acc;
    __syncthreads();
    if (j < 2) {
        float o = clb[j];
        #pragma unroll 4
        for (int k = 0; k < 128; ++k) o = fmaf(feat[k], clw[(size_t)j * 128 + k], o);
        out[b * 2 + j] = o;
    }
}

extern "C" void kernel_launch(void* const* d_in, const int* in_sizes, int n_in,
                              void* d_out, int out_size, void* d_ws, size_t ws_size,
                              hipStream_t stream) {
    const float* x        = (const float*)d_in[0];
    const float* w_ih_l0f = (const float*)d_in[1];
    const float* w_hh_l0f = (const float*)d_in[2];
    const float* b_ih_l0f = (const float*)d_in[3];
    const float* b_hh_l0f = (const float*)d_in[4];
    const float* w_ih_l0b = (const float*)d_in[5];
    const float* w_hh_l0b = (const float*)d_in[6];
    const float* b_ih_l0b = (const float*)d_in[7];
    const float* b_hh_l0b = (const float*)d_in[8];
    const float* w_ih_l1f = (const float*)d_in[9];
    const float* w_hh_l1f = (const float*)d_in[10];
    const float* b_ih_l1f = (const float*)d_in[11];
    const float* b_hh_l1f = (const float*)d_in[12];
    const float* w_ih_l1b = (const float*)d_in[13];
    const float* w_hh_l1b = (const float*)d_in[14];
    const float* b_ih_l1b = (const float*)d_in[15];
    const float* b_hh_l1b = (const float*)d_in[16];
    const float* fc_w     = (const float*)d_in[17];
    const float* fc_b     = (const float*)d_in[18];
    const float* clf_w    = (const float*)d_in[19];
    const float* clf_b    = (const float*)d_in[20];

    char* ws = (char*)d_ws;
    size_t off = 0;
    __hip_bfloat16* X0 = (__hip_bfloat16*)(ws + off); off += (size_t)TT * BB * 128 * 2;  // 32.8 MB
    __hip_bfloat16* y0 = (__hip_bfloat16*)(ws + off); off += (size_t)TT * BB * 256 * 2;  // 65.5 MB
    short* buf[4];  // F0, B0, F1, B1 (ping-pong per parity)
    for (int i = 0; i < 4; ++i) { buf[i] = (short*)(ws + off); off += (size_t)TC * BB * 512 * 2; } // 4x 8.2MB
    __hip_bfloat16* W0 = (__hip_bfloat16*)(ws + off); off += (size_t)1024 * 128 * 2;
    __hip_bfloat16* W1 = (__hip_bfloat16*)(ws + off); off += (size_t)1024 * 256 * 2;
    short* whhF0       = (short*)(ws + off);          off += (size_t)16384 * 8 * 2;
    short* whhF1       = (short*)(ws + off);          off += (size_t)16384 * 8 * 2;
    float* bias0  = (float*)(ws + off); off += 1024 * 4;
    float* bias1  = (float*)(ws + off); off += 1024 * 4;
    float* hstate = (float*)(ws + off); off += 2 * BB * HH * 4;
    float* cstate = (float*)(ws + off); off += 2 * BB * HH * 4;
    // total ~132.5 MB

    conv_x_kernel<<<dim3(TT / 16, BB), 256, 0, stream>>>(x, X0);
    conv_w_kernel<<<1024, 128, 0, stream>>>(w_ih_l0f, w_ih_l0b, b_ih_l0f, b_hh_l0f,
                                            b_ih_l0b, b_hh_l0b, W0, bias0, 98, 128);
    conv_w_kernel<<<1024, 256, 0, stream>>>(w_ih_l1f, w_ih_l1b, b_ih_l1f, b_hh_l1f,
                                            b_ih_l1b, b_hh_l1b, W1, bias1, 256, 256);
    conv_whh_kernel<<<64, 256, 0, stream>>>(w_hh_l0f, w_hh_l0b, whhF0);
    conv_whh_kernel<<<64, 256, 0, stream>>>(w_hh_l1f, w_hh_l1b, whhF1);

    const short* X0s = (const short*)X0;
    const short* y0s = (const short*)y0;
    const short* W0s = (const short*)W0;
    const short* W1s = (const short*)W1;

    // ---- layer 0 ----
    gemm_only_kernel<128><<<2 * TC, 512, 0, stream>>>(X0s, W0s, bias0,
        buf[0], buf[1], 0, (TT - TC) * BB);
    for (int k = 0; k < NCH; ++k) {
        int pr = k & 1, pn = pr ^ 1;
        int ng = (k < NCH - 1) ? 2 * TC : 0;
        fused_kernel<128><<<32 + ng, 512, 0, stream>>>(
            X0s, W0s, bias0, buf[2 * pn], buf[2 * pn + 1],
            (k + 1) * TC * BB, (TT - (k + 2) * TC) * BB,
            buf[2 * pr], buf[2 * pr + 1], whhF0, y0, hstate, cstate,
            k * TC, TT - (k + 1) * TC, 1, k == 0);
    }

    // ---- layer 1 (only final h needed) ----
    gemm_only_kernel<256><<<2 * TC, 512, 0, stream>>>(y0s, W1s, bias1,
        buf[0], buf[1], 0, (TT - TC) * BB);
    for (int k = 0; k < NCH; ++k) {
        int pr = k & 1, pn = pr ^ 1;
        int ng = (k < NCH - 1) ? 2 * TC : 0;
        fused_kernel<256><<<32 + ng, 512, 0, stream>>>(
            y0s, W1s, bias1, buf[2 * pn], buf[2 * pn + 1],
            (k + 1) * TC * BB, (TT - (k + 2) * TC) * BB,
            buf[2 * pr], buf[2 * pr + 1], whhF1, y0 /*unused*/, hstate, cstate,
            k * TC, TT - (k + 1) * TC, 0, k == 0);
    }

    fc_kernel<<<BB, 128, 0, stream>>>(hstate, fc_w, fc_b, clf_w, clf_b, (float*)d_out);
}